// Round 1
// baseline (551.835 us; speedup 1.0000x reference)
//
#include <hip/hip_runtime.h>
#include <hip/hip_bf16.h>
#include <cstdint>

#define VOCAB 4096
#define ORDER 4
#define FAN   16388      // ORDER * (VOCAB + 1)
#define NB    8
#define NL    2048
#define NPOS  (NB * NL)  // 16384

// ---------------------------------------------------------------------------
// Pass 1: Wt[c][v] = bf16(W[v][c]).  64x64 tiles through LDS, both sides
// coalesced.  LDS padded to 65 to kill bank conflicts on transposed read.
// ---------------------------------------------------------------------------
__global__ __launch_bounds__(256) void k_transpose_bf16(
    const float* __restrict__ W, __hip_bfloat16* __restrict__ Wt)
{
    __shared__ float tile[64][65];
    const int c0 = blockIdx.x * 64;          // fan_in dim (16388 -> 257 tiles)
    const int v0 = blockIdx.y * 64;          // vocab dim  (4096 -> 64 tiles)
    const int tx = threadIdx.x & 63;
    const int ty = threadIdx.x >> 6;         // 0..3

    if (c0 + tx < FAN) {
        #pragma unroll
        for (int i = 0; i < 16; ++i) {
            const int vl = ty + 4 * i;
            tile[vl][tx] = W[(size_t)(v0 + vl) * FAN + (c0 + tx)];
        }
    }
    __syncthreads();
    #pragma unroll
    for (int i = 0; i < 16; ++i) {
        const int cl = ty + 4 * i;
        const int c  = c0 + cl;
        if (c < FAN) {
            Wt[(size_t)c * VOCAB + (v0 + tx)] = __float2bfloat16(tile[tx][cl]);
        }
    }
}

// ---------------------------------------------------------------------------
// Pass 2: one block per position; gather 4 contiguous bf16 rows of Wt,
// sum with fp32 bias, write coalesced float4s.
// ---------------------------------------------------------------------------
__device__ __forceinline__ void accum8(float* acc, const uint4& a)
{
    const unsigned w0 = a.x, w1 = a.y, w2 = a.z, w3 = a.w;
    acc[0] += __uint_as_float(w0 << 16);
    acc[1] += __uint_as_float(w0 & 0xFFFF0000u);
    acc[2] += __uint_as_float(w1 << 16);
    acc[3] += __uint_as_float(w1 & 0xFFFF0000u);
    acc[4] += __uint_as_float(w2 << 16);
    acc[5] += __uint_as_float(w2 & 0xFFFF0000u);
    acc[6] += __uint_as_float(w3 << 16);
    acc[7] += __uint_as_float(w3 & 0xFFFF0000u);
}

__global__ __launch_bounds__(256) void k_gather(
    const int* __restrict__ idx, const __hip_bfloat16* __restrict__ Wt,
    const float* __restrict__ bias, float* __restrict__ out)
{
    const int pos = blockIdx.x;
    const int bb  = pos >> 11;               // / NL
    const int ll  = pos & (NL - 1);
    const int* row = idx + bb * NL;

    const uint16_t* r[ORDER];
    #pragma unroll
    for (int k = 0; k < ORDER; ++k) {
        const int s   = ORDER - 1 - k;
        const int tok = (ll >= s) ? row[ll - s] : VOCAB;   // pad token = VOCAB
        r[k] = (const uint16_t*)(Wt + (size_t)(k * (VOCAB + 1) + tok) * VOCAB);
    }

    float* o    = out + (size_t)pos * VOCAB;
    const int j = threadIdx.x;

    #pragma unroll
    for (int seg = 0; seg < 2; ++seg) {
        const int v = seg * 2048 + j * 8;    // 8 consecutive v per thread

        const uint4 a0 = *(const uint4*)(r[0] + v);
        const uint4 a1 = *(const uint4*)(r[1] + v);
        const uint4 a2 = *(const uint4*)(r[2] + v);
        const uint4 a3 = *(const uint4*)(r[3] + v);
        const float4 b0 = *(const float4*)(bias + v);
        const float4 b1 = *(const float4*)(bias + v + 4);

        float acc[8] = {b0.x, b0.y, b0.z, b0.w, b1.x, b1.y, b1.z, b1.w};
        accum8(acc, a0);
        accum8(acc, a1);
        accum8(acc, a2);
        accum8(acc, a3);

        *(float4*)(o + v)     = make_float4(acc[0], acc[1], acc[2], acc[3]);
        *(float4*)(o + v + 4) = make_float4(acc[4], acc[5], acc[6], acc[7]);
    }
}

// ---------------------------------------------------------------------------
// Fallback (ws too small): direct strided reads from W.  Correct, slower.
// ---------------------------------------------------------------------------
__global__ __launch_bounds__(256) void k_direct(
    const int* __restrict__ idx, const float* __restrict__ W,
    const float* __restrict__ bias, float* __restrict__ out)
{
    const int pos = blockIdx.x;
    const int bb  = pos >> 11;
    const int ll  = pos & (NL - 1);
    const int* row = idx + bb * NL;

    int off[ORDER];
    #pragma unroll
    for (int k = 0; k < ORDER; ++k) {
        const int s   = ORDER - 1 - k;
        const int tok = (ll >= s) ? row[ll - s] : VOCAB;
        off[k] = k * (VOCAB + 1) + tok;
    }

    float* o = out + (size_t)pos * VOCAB;
    for (int v = threadIdx.x; v < VOCAB; v += 256) {
        const float* wr = W + (size_t)v * FAN;
        o[v] = bias[v] + wr[off[0]] + wr[off[1]] + wr[off[2]] + wr[off[3]];
    }
}

// ---------------------------------------------------------------------------
extern "C" void kernel_launch(void* const* d_in, const int* in_sizes, int n_in,
                              void* d_out, int out_size, void* d_ws, size_t ws_size,
                              hipStream_t stream)
{
    const int*   idx  = (const int*)d_in[0];
    const float* W    = (const float*)d_in[1];
    const float* bias = (const float*)d_in[2];
    float*       out  = (float*)d_out;

    const size_t wt_bytes = (size_t)FAN * VOCAB * sizeof(__hip_bfloat16); // 134.25 MB

    if (ws_size >= wt_bytes) {
        __hip_bfloat16* Wt = (__hip_bfloat16*)d_ws;
        dim3 g1((FAN + 63) / 64, VOCAB / 64);   // 257 x 64 tiles
        k_transpose_bf16<<<g1, 256, 0, stream>>>(W, Wt);
        k_gather<<<NPOS, 256, 0, stream>>>(idx, Wt, bias, out);
    } else {
        k_direct<<<NPOS, 256, 0, stream>>>(idx, W, bias, out);
    }
}

// Round 2
// 528.426 us; speedup vs baseline: 1.0443x; 1.0443x over previous
//
#include <hip/hip_runtime.h>
#include <hip/hip_bf16.h>
#include <cstdint>

#define VOCAB 4096
#define ORDER 4
#define FAN   16388      // ORDER * (VOCAB + 1)
#define NL    2048
#define NPOS  16384      // B * L

typedef float        f4 __attribute__((ext_vector_type(4)));
typedef unsigned int u4 __attribute__((ext_vector_type(4)));

static __device__ __forceinline__ unsigned short f2bf(float f)
{
    __hip_bfloat16 h = __float2bfloat16(f);
    unsigned short r;
    __builtin_memcpy(&r, &h, 2);
    return r;
}

// ---------------------------------------------------------------------------
// Pass 1: Wt[c][v] = bf16(W[v][c]).  64x64 tile via LDS.
//   reads:  float4 nontemporal (W is dead after this pass — keep L3 for Wt)
//   writes: uint4 = 8 packed bf16, coalesced along v
// ---------------------------------------------------------------------------
__global__ __launch_bounds__(256) void k_transpose_bf16(
    const float* __restrict__ W, unsigned short* __restrict__ Wt)
{
    __shared__ float tile[64][65];            // [v][c], pad 65: 2-way max (free)
    const int c0 = blockIdx.x * 64;           // fan_in tiles: 257
    const int v0 = blockIdx.y * 64;           // vocab tiles: 64

    // ---- load phase: thread reads float4 along c ----
    const int cq = (threadIdx.x & 15) * 4;    // 0..60
    const int vr = threadIdx.x >> 4;          // 0..15
    const bool cvalid = (c0 + cq) < FAN;      // FAN % 4 == 0 -> whole float4 valid

    #pragma unroll
    for (int i = 0; i < 4; ++i) {
        const int v = vr + 16 * i;
        if (cvalid) {
            const f4 f = __builtin_nontemporal_load(
                (const f4*)(W + (size_t)(v0 + v) * FAN + (c0 + cq)));
            tile[v][cq + 0] = f.x;
            tile[v][cq + 1] = f.y;
            tile[v][cq + 2] = f.z;
            tile[v][cq + 3] = f.w;
        }
    }
    __syncthreads();

    // ---- store phase: thread writes 8 consecutive v (packed bf16) for one c ----
    const int p  = (threadIdx.x & 7) * 8;     // v offset 0..56
    const int cb = threadIdx.x >> 3;          // 0..31

    #pragma unroll
    for (int i = 0; i < 2; ++i) {
        const int cl = cb + 32 * i;
        const int c  = c0 + cl;
        if (c < FAN) {
            unsigned short s[8];
            #pragma unroll
            for (int j = 0; j < 8; ++j)
                s[j] = f2bf(tile[p + j][cl]);  // bank = (v + c) % 32 -> 2-way, free
            u4 pk;
            pk.x = (unsigned)s[0] | ((unsigned)s[1] << 16);
            pk.y = (unsigned)s[2] | ((unsigned)s[3] << 16);
            pk.z = (unsigned)s[4] | ((unsigned)s[5] << 16);
            pk.w = (unsigned)s[6] | ((unsigned)s[7] << 16);
            *(u4*)(Wt + (size_t)c * VOCAB + v0 + p) = pk;
        }
    }
}

// ---------------------------------------------------------------------------
// Pass 2: one block per position; gather 4 contiguous bf16 rows of Wt,
// sum with fp32 bias, nontemporal float4 stores (keep Wt L3-resident).
// ---------------------------------------------------------------------------
__device__ __forceinline__ void accum8(float* acc, const u4& a)
{
    const unsigned w0 = a.x, w1 = a.y, w2 = a.z, w3 = a.w;
    acc[0] += __uint_as_float(w0 << 16);
    acc[1] += __uint_as_float(w0 & 0xFFFF0000u);
    acc[2] += __uint_as_float(w1 << 16);
    acc[3] += __uint_as_float(w1 & 0xFFFF0000u);
    acc[4] += __uint_as_float(w2 << 16);
    acc[5] += __uint_as_float(w2 & 0xFFFF0000u);
    acc[6] += __uint_as_float(w3 << 16);
    acc[7] += __uint_as_float(w3 & 0xFFFF0000u);
}

__global__ __launch_bounds__(256) void k_gather(
    const int* __restrict__ idx, const unsigned short* __restrict__ Wt,
    const float* __restrict__ bias, float* __restrict__ out)
{
    const int pos = blockIdx.x;
    const int bb  = pos >> 11;                // / NL
    const int ll  = pos & (NL - 1);
    const int* row = idx + bb * NL;

    const unsigned short* r[ORDER];
    #pragma unroll
    for (int k = 0; k < ORDER; ++k) {
        const int s   = ORDER - 1 - k;
        const int tok = (ll >= s) ? row[ll - s] : VOCAB;   // pad token = VOCAB
        r[k] = Wt + (size_t)(k * (VOCAB + 1) + tok) * VOCAB;
    }

    float* o    = out + (size_t)pos * VOCAB;
    const int j = threadIdx.x;

    #pragma unroll
    for (int seg = 0; seg < 2; ++seg) {
        const int v = seg * 2048 + j * 8;     // 8 consecutive v per thread

        const u4 a0 = *(const u4*)(r[0] + v);
        const u4 a1 = *(const u4*)(r[1] + v);
        const u4 a2 = *(const u4*)(r[2] + v);
        const u4 a3 = *(const u4*)(r[3] + v);
        const f4 b0 = *(const f4*)(bias + v);
        const f4 b1 = *(const f4*)(bias + v + 4);

        float acc[8] = {b0.x, b0.y, b0.z, b0.w, b1.x, b1.y, b1.z, b1.w};
        accum8(acc, a0);
        accum8(acc, a1);
        accum8(acc, a2);
        accum8(acc, a3);

        f4 o0; o0.x = acc[0]; o0.y = acc[1]; o0.z = acc[2]; o0.w = acc[3];
        f4 o1; o1.x = acc[4]; o1.y = acc[5]; o1.z = acc[6]; o1.w = acc[7];
        __builtin_nontemporal_store(o0, (f4*)(o + v));
        __builtin_nontemporal_store(o1, (f4*)(o + v + 4));
    }
}

// ---------------------------------------------------------------------------
// Fallback (ws too small): direct strided reads from W.  Correct, slower.
// ---------------------------------------------------------------------------
__global__ __launch_bounds__(256) void k_direct(
    const int* __restrict__ idx, const float* __restrict__ W,
    const float* __restrict__ bias, float* __restrict__ out)
{
    const int pos = blockIdx.x;
    const int bb  = pos >> 11;
    const int ll  = pos & (NL - 1);
    const int* row = idx + bb * NL;

    int off[ORDER];
    #pragma unroll
    for (int k = 0; k < ORDER; ++k) {
        const int s   = ORDER - 1 - k;
        const int tok = (ll >= s) ? row[ll - s] : VOCAB;
        off[k] = k * (VOCAB + 1) + tok;
    }

    float* o = out + (size_t)pos * VOCAB;
    for (int v = threadIdx.x; v < VOCAB; v += 256) {
        const float* wr = W + (size_t)v * FAN;
        o[v] = bias[v] + wr[off[0]] + wr[off[1]] + wr[off[2]] + wr[off[3]];
    }
}

// ---------------------------------------------------------------------------
extern "C" void kernel_launch(void* const* d_in, const int* in_sizes, int n_in,
                              void* d_out, int out_size, void* d_ws, size_t ws_size,
                              hipStream_t stream)
{
    const int*   idx  = (const int*)d_in[0];
    const float* W    = (const float*)d_in[1];
    const float* bias = (const float*)d_in[2];
    float*       out  = (float*)d_out;

    const size_t wt_bytes = (size_t)FAN * VOCAB * 2;   // 134.25 MB

    if (ws_size >= wt_bytes) {
        unsigned short* Wt = (unsigned short*)d_ws;
        dim3 g1((FAN + 63) / 64, VOCAB / 64);          // 257 x 64 tiles
        k_transpose_bf16<<<g1, 256, 0, stream>>>(W, Wt);
        k_gather<<<NPOS, 256, 0, stream>>>(idx, Wt, bias, out);
    } else {
        k_direct<<<NPOS, 256, 0, stream>>>(idx, W, bias, out);
    }
}